// Round 22
// baseline (95.148 us; speedup 1.0000x reference)
//
#include <hip/hip_runtime.h>
#include <hip/hip_fp16.h>

// RotMat forward: 511 rounds of 256 disjoint Givens rotations on rows of a
// [512, 1024] fp32 matrix (round-robin tournament schedule).
//
// R21: S=4 SEGMENT DECOMPOSITION + TLP everywhere.
// out = Q3*(Q2*(Q1*(Q0*x))); Q0=rounds 0..127, Q1=128..255, Q2=256..383,
// Q3=384..510. Build: 2048 column-tasks (4 segs x 512 identity cols) = 512
// blocks = 2 blocks/CU = 2 waves/SIMD TLP; depth 128 (1/4 the monolithic's
// serial rounds). Segs 0-2 end with R20-proven CHUNK16_TAIL; seg3 with
// R19-proven CHUNK15_TAIL. seg3 write map = player_of(511,.) = identity.
// Apply: 4 GEMMs with 16x64 tiles, 512 blocks = 2 blocks/CU (R20's GEMM ran
// 1 wave/SIMD solo-issue at ~15us; this is the fix), chained through ONE Y
// buffer: x->Y->out->Y->out. ws need: 512K table + 4MB Q + 2MB Y = 6.8MB;
// fallback to proven monolithic (46.4us) if ws too small.

#define N_COLS   1024
#define PAIRS    256

typedef __attribute__((ext_vector_type(4))) float f32x4;

// ---- setup: f16-packed (c,s) table, round r at byte r*1024, pair k at +k*4.
__global__ __launch_bounds__(256) void rotmat_setup(const float* __restrict__ thetas,
                                                    __half2* __restrict__ cs16) {
    const int r = blockIdx.x;   // 0..510
    const int k = threadIdx.x;  // 0..255
    int pu = (k == 0) ? 0 : ((k - 1 - r + 1022) % 511) + 1;
    int pv = ((510 - k - r + 1022) % 511) + 1;
    int i = min(pu, pv), j = max(pu, pv);
    int t = i * 511 - (i * (i - 1)) / 2 + (j - i - 1);
    float s, c;
    sincosf(thetas[t], &s, &c);
    float sp = (pu < pv) ? s : -s;
    cs16[r * 256 + k] = __floats2half2_rn(c, sp);
}

__device__ __forceinline__ float dpp_shr1(float old, float src) {
    return __int_as_float(__builtin_amdgcn_update_dpp(
        __float_as_int(old), __float_as_int(src), 0x138, 0xF, 0xF, false));
}
__device__ __forceinline__ float dpp_shl1(float old, float src) {
    return __int_as_float(__builtin_amdgcn_update_dpp(
        __float_as_int(old), __float_as_int(src), 0x130, 0xF, 0xF, false));
}
__device__ __forceinline__ void glds16(const void* g, void* l) {
    __builtin_amdgcn_global_load_lds(
        (const __attribute__((address_space(1))) void*)g,
        (__attribute__((address_space(3))) void*)l, 16, 0, 0);
}

// v_fma_mix_f32 coefficient consumption (R16-validated).
#define FMIX_SN(d, P, x)                                                      \
    asm("v_fma_mix_f32 %0, -%1, %2, 0 op_sel:[1,0,0] op_sel_hi:[1,0,0]"       \
        : "=v"(d) : "v"(P), "v"(x));
#define FMIX_SP(d, P, x)                                                      \
    asm("v_fma_mix_f32 %0, %1, %2, 0 op_sel:[1,0,0] op_sel_hi:[1,0,0]"        \
        : "=v"(d) : "v"(P), "v"(x));
#define FMIX_C(d, P, x, a)                                                    \
    asm("v_fma_mix_f32 %0, %1, %2, %3 op_sel:[0,0,0] op_sel_hi:[1,0,0]"       \
        : "=v"(d) : "v"(P), "v"(x), "v"(a));

#define ROUND(AA)                                                  \
    {                                                              \
        float P0 = (AA).x, P1 = (AA).y, P2 = (AA).z, P3 = (AA).w;  \
        float t3, u3, l3, h3, t0, u0, l0, h0;                      \
        FMIX_SN(t3, P3, hi[3])                                     \
        FMIX_C(l3, P3, lo[3], t3)                                  \
        FMIX_SP(u3, P3, lo[3])                                     \
        FMIX_C(h3, P3, hi[3], u3)                                  \
        FMIX_SN(t0, P0, hi[0])                                     \
        FMIX_C(l0, P0, lo[0], t0)                                  \
        FMIX_SP(u0, P0, lo[0])                                     \
        FMIX_C(h0, P0, hi[0], u0)                                  \
        float nlo0 = dpp_shr1(l0, l3);                             \
        float nhi3 = dpp_shl1(l3, h0);                             \
        float t1, u1, l1, h1, t2, u2, l2, h2;                      \
        FMIX_SN(t1, P1, hi[1])                                     \
        FMIX_C(l1, P1, lo[1], t1)                                  \
        FMIX_SP(u1, P1, lo[1])                                     \
        FMIX_C(h1, P1, hi[1], u1)                                  \
        FMIX_SN(t2, P2, hi[2])                                     \
        FMIX_C(l2, P2, lo[2], t2)                                  \
        FMIX_SP(u2, P2, lo[2])                                     \
        FMIX_C(h2, P2, hi[2], u2)                                  \
        float nlo1 = is0 ? h0 : l0;                                \
        lo[0] = nlo0; lo[1] = nlo1; lo[2] = l1; lo[3] = l2;        \
        hi[0] = h1; hi[1] = h2; hi[2] = h3; hi[3] = nhi3;          \
    }

#define DSRD(dst, addr, imm)                                   \
    asm volatile("ds_read_b128 %0, %1 offset:%c2"              \
                 : "=v"(dst) : "v"(addr), "i"(imm))
#define WL3(a) asm volatile("s_waitcnt lgkmcnt(3)" : "+v"(a))
#define WL2(a) asm volatile("s_waitcnt lgkmcnt(2)" : "+v"(a))
#define WL1(a) asm volatile("s_waitcnt lgkmcnt(1)" : "+v"(a))
#define WL0(a) asm volatile("s_waitcnt lgkmcnt(0)" : "+v"(a))
#define WAITV(n) asm volatile("s_waitcnt vmcnt(" #n ")" ::: "memory")
#define BAR()                               \
    __builtin_amdgcn_s_barrier();           \
    __builtin_amdgcn_sched_barrier(0)

#define STAGE(cix, bix)                                              \
    {                                                                \
        const char* g_ = gsrc + (size_t)(cix)*16384;                 \
        char* l_ = lb + (size_t)(bix)*16384;                         \
        _Pragma("unroll")                                            \
        for (int j_ = 0; j_ < 4; ++j_)                               \
            glds16(g_ + j_ * 1024, l_ + j_ * 1024);                  \
    }

#define CHUNK16(ACUR, ANXT)                                    \
    WL3(A0); ROUND(A0) DSRD(A0, ACUR,  4 * 1024);              \
    WL3(A1); ROUND(A1) DSRD(A1, ACUR,  5 * 1024);              \
    WL3(A2); ROUND(A2) DSRD(A2, ACUR,  6 * 1024);              \
    WL3(A3); ROUND(A3) DSRD(A3, ACUR,  7 * 1024);              \
    WL3(A0); ROUND(A0) DSRD(A0, ACUR,  8 * 1024);              \
    WL3(A1); ROUND(A1) DSRD(A1, ACUR,  9 * 1024);              \
    WL3(A2); ROUND(A2) DSRD(A2, ACUR, 10 * 1024);              \
    WL3(A3); ROUND(A3) DSRD(A3, ACUR, 11 * 1024);              \
    WL3(A0); ROUND(A0) DSRD(A0, ACUR, 12 * 1024);              \
    WL3(A1); ROUND(A1) DSRD(A1, ACUR, 13 * 1024);              \
    WL3(A2); ROUND(A2) DSRD(A2, ACUR, 14 * 1024);              \
    WL3(A3); ROUND(A3) DSRD(A3, ACUR, 15 * 1024);              \
    WL3(A0); ROUND(A0) DSRD(A0, ANXT,  0 * 1024);              \
    WL3(A1); ROUND(A1) DSRD(A1, ANXT,  1 * 1024);              \
    WL3(A2); ROUND(A2) DSRD(A2, ANXT,  2 * 1024);              \
    WL3(A3); ROUND(A3) DSRD(A3, ANXT,  3 * 1024);

// 15-round tail (rel 112..126; rel 127 staged, never read). Drained. [R19]
#define CHUNK15_TAIL(ACUR)                                     \
    WL3(A0); ROUND(A0) DSRD(A0, ACUR,  4 * 1024);              \
    WL3(A1); ROUND(A1) DSRD(A1, ACUR,  5 * 1024);              \
    WL3(A2); ROUND(A2) DSRD(A2, ACUR,  6 * 1024);              \
    WL3(A3); ROUND(A3) DSRD(A3, ACUR,  7 * 1024);              \
    WL3(A0); ROUND(A0) DSRD(A0, ACUR,  8 * 1024);              \
    WL3(A1); ROUND(A1) DSRD(A1, ACUR,  9 * 1024);              \
    WL3(A2); ROUND(A2) DSRD(A2, ACUR, 10 * 1024);              \
    WL3(A3); ROUND(A3) DSRD(A3, ACUR, 11 * 1024);              \
    WL3(A0); ROUND(A0) DSRD(A0, ACUR, 12 * 1024);              \
    WL3(A1); ROUND(A1) DSRD(A1, ACUR, 13 * 1024);              \
    WL3(A2); ROUND(A2) DSRD(A2, ACUR, 14 * 1024);              \
    WL3(A3); ROUND(A3)                                         \
    WL2(A0); ROUND(A0)                                         \
    WL1(A1); ROUND(A1)                                         \
    WL0(A2); ROUND(A2)

// 16-round tail (rel 112..127, all consumed, no dead reads). Drained. [R20]
#define CHUNK16_TAIL(ACUR)                                     \
    WL3(A0); ROUND(A0) DSRD(A0, ACUR,  4 * 1024);              \
    WL3(A1); ROUND(A1) DSRD(A1, ACUR,  5 * 1024);              \
    WL3(A2); ROUND(A2) DSRD(A2, ACUR,  6 * 1024);              \
    WL3(A3); ROUND(A3) DSRD(A3, ACUR,  7 * 1024);              \
    WL3(A0); ROUND(A0) DSRD(A0, ACUR,  8 * 1024);              \
    WL3(A1); ROUND(A1) DSRD(A1, ACUR,  9 * 1024);              \
    WL3(A2); ROUND(A2) DSRD(A2, ACUR, 10 * 1024);              \
    WL3(A3); ROUND(A3) DSRD(A3, ACUR, 11 * 1024);              \
    WL3(A0); ROUND(A0) DSRD(A0, ACUR, 12 * 1024);              \
    WL3(A1); ROUND(A1) DSRD(A1, ACUR, 13 * 1024);              \
    WL3(A2); ROUND(A2) DSRD(A2, ACUR, 14 * 1024);              \
    WL3(A3); ROUND(A3) DSRD(A3, ACUR, 15 * 1024);              \
    WL3(A0); ROUND(A0)                                         \
    WL2(A1); ROUND(A1)                                         \
    WL1(A2); ROUND(A2)                                         \
    WL0(A3); ROUND(A3)

// player(r, p): row carried at position p at the start of round r.
// player(511, p) == p (identity).
__device__ __forceinline__ int player_of(int r, int p) {
    return (p == 0) ? 0 : ((p - 1 - r + 1022 * 2) % 511) + 1;
}

// ---- build: 4 segment operators, 2048 waves (512 blocks, 2 blocks/CU) ----
// seg = wid>>9 (block-uniform), j = wid&511. seg s: rounds 128s..min(128s+
// 127,510). QT[seg][j][row], K-major. 8 chunks of 16 rounds.
__global__ __launch_bounds__(256, 2) void rotmat_build(const __half2* __restrict__ cs16,
                                                       float* __restrict__ qt) {
    __shared__ f32x4 tab[3 * 1024];  // 48KB -> 2 blocks/CU co-resident

    const int lane = threadIdx.x & 63;
    const int wave = threadIdx.x >> 6;
    const int wid  = (blockIdx.x << 2) + wave;
    const int seg  = wid >> 9;            // 0..3 (uniform per block)
    const int j    = wid & 511;
    const int r0   = seg << 7;            // 0,128,256,384
    const int k0   = lane << 2;
    const bool is0 = (lane == 0);

    float lo[4], hi[4];
#pragma unroll
    for (int m = 0; m < 4; ++m) {
        int p = k0 + m, pq = 511 - p;
        lo[m] = (player_of(r0, p) == j) ? 1.0f : 0.0f;
        hi[m] = (player_of(r0, pq) == j) ? 1.0f : 0.0f;
    }

    const char* gsrc = (const char*)cs16 + (size_t)r0 * 1024
                     + (size_t)wave * 4096 + (size_t)lane * 16;
    char* lb = (char*)(&tab[0]) + (size_t)wave * 4096;
    unsigned ldsLane;
    {
        auto p3 = (__attribute__((address_space(3))) char*)(&tab[0]);
        ldsLane = (unsigned)(size_t)p3 + (unsigned)(lane * 16);
    }

    f32x4 A0, A1, A2, A3;

    STAGE(0, 0)
    STAGE(1, 1)
    WAITV(0);
    BAR();
    {
        unsigned a0 = ldsLane;
        DSRD(A0, a0, 0 * 1024);
        DSRD(A1, a0, 1 * 1024);
        DSRD(A2, a0, 2 * 1024);
        DSRD(A3, a0, 3 * 1024);
    }

    // 8 chunks. Chunks 0..5 stage c+2; chunk 6 (no stage); chunk 7 tail.
    // segs 0-2: 7xCHUNK16 + CHUNK16_TAIL = 128 rounds. seg3: 7xCHUNK16 +
    // CHUNK15_TAIL = 127 rounds (rel 127 = abs 511 pad staged, never read).
    int bufCur = 0, bufNxt = 1, bufStg = 2;
    for (int c = 0; c < 6; ++c) {
        WAITV(0);
        BAR();
        STAGE(c + 2, bufStg)
        unsigned aCur = ldsLane + (unsigned)bufCur * 16384u;
        unsigned aNxt = ldsLane + (unsigned)bufNxt * 16384u;
        CHUNK16(aCur, aNxt)
        int t_ = bufCur; bufCur = bufNxt; bufNxt = bufStg; bufStg = t_;
    }
    {
        WAITV(0);   // stage(7) landed (issued at c=5)
        BAR();
        unsigned aCur = ldsLane + (unsigned)bufCur * 16384u;
        unsigned aNxt = ldsLane + (unsigned)bufNxt * 16384u;
        CHUNK16(aCur, aNxt)
        int t_ = bufCur; bufCur = bufNxt; bufNxt = bufStg; bufStg = t_;
    }
    {
        unsigned aCur = ldsLane + (unsigned)bufCur * 16384u;
        if (seg < 3) {
            CHUNK16_TAIL(aCur)
        } else {
            CHUNK15_TAIL(aCur)
        }
    }

    // Write Q_seg^T: row = player(r1, p). seg3: r1=511 (identity map).
    const int r1 = (seg == 3) ? 511 : (r0 + 128);
    float* qv = qt + (size_t)seg * 262144 + (size_t)j * 512;
#pragma unroll
    for (int m = 0; m < 4; ++m) {
        int p = k0 + m, pq = 511 - p;
        qv[player_of(r1, p)]  = lo[m];
        qv[player_of(r1, pq)] = hi[m];
    }
}

// ---- apply: C[512][1024] = sum_j AT[j][row] * B[j][col] -------------------
// AT K-major [512][512]; B row-major [512][1024]. BM=16, BN=64, BK=32.
// 512 blocks (32 row-tiles x 16 col-tiles) = 2 blocks/CU = 2 waves/SIMD TLP.
// Software-pipelined staging (register prefetch of tile kt+1).
__global__ __launch_bounds__(256) void gemm_qt(const float* __restrict__ AT,
                                               const float* __restrict__ B,
                                               float* __restrict__ C) {
    __shared__ float As[32][16];   // [k][m]  2KB
    __shared__ float Bs[32][64];   // [k][n]  8KB

    const int t    = threadIdx.x;
    const int bx   = blockIdx.x & 15;   // col tile (64 wide)
    const int by   = blockIdx.x >> 4;   // row tile (16 tall), 0..31
    const int row0 = by * 16, col0 = bx * 64;
    const int mr   = t >> 4;            // 0..15 (1 row per thread)
    const int nc   = (t & 15) * 4;      // 4 cols

    const int kkA = t >> 2, mmA = (t & 3) * 4;   // As stage coords (t<128)
    const int kkB = t >> 4, ccB = (t & 15) * 4;  // Bs stage coords

    float acc0 = 0, acc1 = 0, acc2 = 0, acc3 = 0;

    float4 pa = make_float4(0.f, 0.f, 0.f, 0.f), pb0, pb1;
    if (t < 128)
        pa = *(const float4*)&AT[(size_t)kkA * 512 + row0 + mmA];
    pb0 = *(const float4*)&B[(size_t)kkB * 1024 + col0 + ccB];
    pb1 = *(const float4*)&B[(size_t)(kkB + 16) * 1024 + col0 + ccB];

    for (int kt = 0; kt < 16; ++kt) {
        __syncthreads();   // previous tile's compute done
        if (t < 128) *(float4*)&As[kkA][mmA] = pa;
        *(float4*)&Bs[kkB][ccB] = pb0;
        *(float4*)&Bs[kkB + 16][ccB] = pb1;
        __syncthreads();
        if (kt < 15) {     // prefetch next tile; latency hides under compute
            if (t < 128)
                pa = *(const float4*)&AT[(size_t)((kt + 1) * 32 + kkA) * 512 + row0 + mmA];
            pb0 = *(const float4*)&B[(size_t)((kt + 1) * 32 + kkB) * 1024 + col0 + ccB];
            pb1 = *(const float4*)&B[(size_t)((kt + 1) * 32 + kkB + 16) * 1024 + col0 + ccB];
        }
#pragma unroll
        for (int kk = 0; kk < 32; ++kk) {
            float a  = As[kk][mr];
            float4 b = *(float4*)&Bs[kk][nc];
            acc0 = fmaf(a, b.x, acc0); acc1 = fmaf(a, b.y, acc1);
            acc2 = fmaf(a, b.z, acc2); acc3 = fmaf(a, b.w, acc3);
        }
    }
    *(float4*)&C[(size_t)(row0 + mr) * 1024 + col0 + nc] =
        make_float4(acc0, acc1, acc2, acc3);
}

// ---- fallback monolithic kernel (R16-proven, 46.4us) ----------------------
// Uses 16-chunk schedule; CHUNK15_TAIL here covers rel 240..254.
template <bool TAB>
__global__ __launch_bounds__(256, 1) void rotmat_main(const float* __restrict__ x,
                                                      const float* __restrict__ thetas,
                                                      const __half2* __restrict__ cs16,
                                                      float* __restrict__ out) {
    __shared__ f32x4 tab[3 * 1024];

    const int lane = threadIdx.x & 63;
    const int wave = threadIdx.x >> 6;
    const int col  = (blockIdx.x << 2) + wave;
    const int k0   = lane << 2;
    const bool is0 = (lane == 0);

    float lo[4], hi[4];
#pragma unroll
    for (int m = 0; m < 4; ++m) {
        lo[m] = x[(k0 + m) * N_COLS + col];
        hi[m] = x[(511 - k0 - m) * N_COLS + col];
    }

    if constexpr (TAB) {
        const char* gsrc = (const char*)cs16 + (size_t)wave * 4096 + (size_t)lane * 16;
        char* lb = (char*)(&tab[0]) + (size_t)wave * 4096;
        unsigned ldsLane;
        {
            auto p3 = (__attribute__((address_space(3))) char*)(&tab[0]);
            ldsLane = (unsigned)(size_t)p3 + (unsigned)(lane * 16);
        }
        f32x4 A0, A1, A2, A3;
        STAGE(0, 0)
        STAGE(1, 1)
        WAITV(0);
        BAR();
        {
            unsigned a0 = ldsLane;
            DSRD(A0, a0, 0 * 1024);
            DSRD(A1, a0, 1 * 1024);
            DSRD(A2, a0, 2 * 1024);
            DSRD(A3, a0, 3 * 1024);
        }
        int bufCur = 0, bufNxt = 1, bufStg = 2;
        for (int c = 0; c < 30; ++c) {
            WAITV(0);
            BAR();
            STAGE(c + 2, bufStg)
            unsigned aCur = ldsLane + (unsigned)bufCur * 16384u;
            unsigned aNxt = ldsLane + (unsigned)bufNxt * 16384u;
            CHUNK16(aCur, aNxt)
            int t_ = bufCur; bufCur = bufNxt; bufNxt = bufStg; bufStg = t_;
        }
        {
            WAITV(0);
            BAR();
            unsigned aCur = ldsLane + (unsigned)bufCur * 16384u;
            unsigned aNxt = ldsLane + (unsigned)bufNxt * 16384u;
            CHUNK16(aCur, aNxt)
            int t_ = bufCur; bufCur = bufNxt; bufNxt = bufStg; bufStg = t_;
        }
        {
            unsigned aCur = ldsLane + (unsigned)bufCur * 16384u;
            CHUNK15_TAIL(aCur)
        }
    } else {
        int pu[4], pv[4];
#pragma unroll
        for (int m = 0; m < 4; ++m) {
            pu[m] = (k0 + m == 0) ? 0 : (k0 + m);
            pv[m] = 511 - (k0 + m);
        }
        for (int r = 0; r < 511; ++r) {
            float cc[4], ss[4];
#pragma unroll
            for (int m = 0; m < 4; ++m) {
                int i = min(pu[m], pv[m]), jj = max(pu[m], pv[m]);
                int t = i * 511 - (i * (i - 1)) / 2 + (jj - i - 1);
                float s, c;
                sincosf(thetas[t], &s, &c);
                cc[m] = c;
                ss[m] = (pu[m] < pv[m]) ? s : -s;
            }
            {
                float t3 = ss[3] * hi[3], u3 = ss[3] * lo[3];
                float l3 = fmaf(cc[3], lo[3], -t3);
                float h3 = fmaf(cc[3], hi[3], u3);
                float t0 = ss[0] * hi[0], u0 = ss[0] * lo[0];
                float l0 = fmaf(cc[0], lo[0], -t0);
                float h0 = fmaf(cc[0], hi[0], u0);
                float nlo0 = dpp_shr1(l0, l3);
                float nhi3 = dpp_shl1(l3, h0);
                float t1 = ss[1] * hi[1], u1 = ss[1] * lo[1];
                float l1 = fmaf(cc[1], lo[1], -t1);
                float h1 = fmaf(cc[1], hi[1], u1);
                float t2 = ss[2] * hi[2], u2 = ss[2] * lo[2];
                float l2 = fmaf(cc[2], lo[2], -t2);
                float h2 = fmaf(cc[2], hi[2], u2);
                float nlo1 = is0 ? h0 : l0;
                lo[0] = nlo0; lo[1] = nlo1; lo[2] = l1; lo[3] = l2;
                hi[0] = h1; hi[1] = h2; hi[2] = h3; hi[3] = nhi3;
            }
#pragma unroll
            for (int m = 0; m < 4; ++m) {
                pu[m] = (k0 + m == 0) ? 0 : ((pu[m] == 1) ? 511 : pu[m] - 1);
                pv[m] = (pv[m] == 1) ? 511 : pv[m] - 1;
            }
        }
    }

#pragma unroll
    for (int m = 0; m < 4; ++m) {
        out[(k0 + m) * N_COLS + col]       = lo[m];
        out[(511 - k0 - m) * N_COLS + col] = hi[m];
    }
}

extern "C" void kernel_launch(void* const* d_in, const int* in_sizes, int n_in,
                              void* d_out, int out_size, void* d_ws, size_t ws_size,
                              hipStream_t stream) {
    const float* x  = (const float*)d_in[0];
    const float* th = (const float*)d_in[1];
    float* out      = (float*)d_out;

    const size_t TAB_B = (size_t)512 * 1024;          // 512 KiB f16 table
    const size_t Q_B   = (size_t)512 * 512 * 4;       // 1 MiB per segment
    const size_t Y_B   = (size_t)512 * 1024 * 4;      // 2 MiB intermediate
    const size_t need_s4 = TAB_B + 4 * Q_B + Y_B;     // 6,815,744

    if (ws_size >= need_s4) {
        __half2* cs16 = (__half2*)d_ws;
        float* qt = (float*)((char*)d_ws + TAB_B);          // Q0T..Q3T
        float* Y  = (float*)((char*)d_ws + TAB_B + 4 * Q_B);
        rotmat_setup<<<511, PAIRS, 0, stream>>>(th, cs16);
        rotmat_build<<<512, 256, 0, stream>>>(cs16, qt);
        gemm_qt<<<512, 256, 0, stream>>>(qt,          x,   Y);    // Y = Q0 x
        gemm_qt<<<512, 256, 0, stream>>>(qt + 262144, Y,   out);  // out = Q1 Y
        gemm_qt<<<512, 256, 0, stream>>>(qt + 524288, out, Y);    // Y = Q2 out
        gemm_qt<<<512, 256, 0, stream>>>(qt + 786432, Y,   out);  // out = Q3 Y
    } else if (ws_size >= TAB_B) {
        __half2* cs16 = (__half2*)d_ws;
        rotmat_setup<<<511, PAIRS, 0, stream>>>(th, cs16);
        rotmat_main<true><<<N_COLS / 4, 256, 0, stream>>>(x, th, cs16, out);
    } else {
        rotmat_main<false><<<N_COLS / 4, 256, 0, stream>>>(x, th, nullptr, out);
    }
}